// Round 3
// baseline (148.829 us; speedup 1.0000x reference)
//
#include <hip/hip_runtime.h>
#include <hip/hip_bf16.h>
#include <cstdint>
#include <cstddef>

#define BATCH 32
#define CH    256
#define NSP   4096          // 64*64 spatial
#define RED   64            // CH / 4
#define GAMMA 0.5f
#define NSPLIT 4            // split-K factor
#define KSEG  (NSP / NSPLIT)      // 1024
#define NKT   (KSEG / 64)         // 16 K-iters of 64
#define TILE_ELEMS (128 * 128)
#define SLICE_STRIDE ((size_t)BATCH * 4 * TILE_ELEMS)   // elems per split slice

typedef float f32x4 __attribute__((ext_vector_type(4)));
typedef short short8 __attribute__((ext_vector_type(8)));

static __device__ inline unsigned short bfu(float f) {
  __hip_bfloat16 h = __float2bfloat16(f);   // RNE; compiler emits v_cvt_pk_bf16_f32
  return __builtin_bit_cast(unsigned short, h);
}

// ---------------------------------------------------------------------------
// K1: split-K partial Gram. grid = 32 b * 4 tiles * 4 splits = 512 blocks
//     (2 blocks/CU for block-level latency hiding), 512 threads (8 waves,
//     2x4 wave grid), 128x128 tile, BK=64, bf16 MFMA.
//     gpart[s][b][tile][128][128] (f32)
// ---------------------------------------------------------------------------
__global__ __launch_bounds__(512, 4)   // 4 waves/EU min = 2 blocks/CU
void gram_partial_kernel(const float* __restrict__ x, float* __restrict__ gpart) {
  const int bx   = blockIdx.x;       // 0..511
  const int s    = bx & 3;
  const int tile = (bx >> 2) & 3;
  const int b    = bx >> 4;
  const int tr   = tile >> 1;
  const int tc   = tile & 1;
  const int tid  = threadIdx.x;
  const int lane = tid & 63;
  const int wave = tid >> 6;
  const int wr   = wave >> 2;        // 0..1  (64-row half)
  const int wc   = wave & 3;         // 0..3  (32-col quarter)

  __shared__ unsigned short lA[128 * 64];    // 16 KiB, XOR-swizzled bf16
  __shared__ unsigned short lB[128 * 64];    // 16 KiB

  const int rsub = tid >> 4;   // 0..31 (row within 32-row group)
  const int c4   = tid & 15;   // float4 column index (64 floats per K-slab row)

  const float* baseA = x + (size_t)(b * CH + tr * 128) * NSP + s * KSEG;
  const float* baseB = x + (size_t)(b * CH + tc * 128) * NSP + s * KSEG;

  f32x4 pa[4], pb[4];
  // prologue: K-tile 0 into registers
#pragma unroll
  for (int i = 0; i < 4; ++i) {
    int row = i * 32 + rsub;
    pa[i] = *reinterpret_cast<const f32x4*>(baseA + (size_t)row * NSP + c4 * 4);
    pb[i] = *reinterpret_cast<const f32x4*>(baseB + (size_t)row * NSP + c4 * 4);
  }

  f32x4 acc[4][2];
#pragma unroll
  for (int m = 0; m < 4; ++m)
#pragma unroll
    for (int n = 0; n < 2; ++n)
      acc[m][n] = (f32x4){0.f, 0.f, 0.f, 0.f};

  char* cA = (char*)lA;
  char* cB = (char*)lB;

  for (int kt = 0; kt < NKT; ++kt) {
    __syncthreads();   // previous iteration's frags fully consumed
    // ---- convert staged registers to bf16 and write to LDS (swizzled) ----
#pragma unroll
    for (int i = 0; i < 4; ++i) {
      int row = i * 32 + rsub;
      int byte = row * 128 + c4 * 8;
      byte ^= (row & 7) << 4;

      uint64_t wa = (uint64_t)bfu(pa[i][0]) | ((uint64_t)bfu(pa[i][1]) << 16) |
                    ((uint64_t)bfu(pa[i][2]) << 32) | ((uint64_t)bfu(pa[i][3]) << 48);
      *reinterpret_cast<uint64_t*>(cA + byte) = wa;

      uint64_t wb = (uint64_t)bfu(pb[i][0]) | ((uint64_t)bfu(pb[i][1]) << 16) |
                    ((uint64_t)bfu(pb[i][2]) << 32) | ((uint64_t)bfu(pb[i][3]) << 48);
      *reinterpret_cast<uint64_t*>(cB + byte) = wb;
    }
    __syncthreads();

    // ---- prefetch next K-slab into registers (overlaps MFMA below) ----
    if (kt + 1 < NKT) {
      const float* kA = baseA + (kt + 1) * 64;
      const float* kB = baseB + (kt + 1) * 64;
#pragma unroll
      for (int i = 0; i < 4; ++i) {
        int row = i * 32 + rsub;
        pa[i] = *reinterpret_cast<const f32x4*>(kA + (size_t)row * NSP + c4 * 4);
        pb[i] = *reinterpret_cast<const f32x4*>(kB + (size_t)row * NSP + c4 * 4);
      }
    }

    // ---- LDS -> fragments ----
    short8 af[4][2], bff[2][2];
#pragma unroll
    for (int m = 0; m < 4; ++m)
#pragma unroll
      for (int kh = 0; kh < 2; ++kh) {
        int rowa = wr * 64 + m * 16 + (lane & 15);
        int bytea = rowa * 128 + kh * 64 + ((lane >> 4) * 16);
        bytea ^= (rowa & 7) << 4;
        af[m][kh] = *reinterpret_cast<const short8*>(cA + bytea);
      }
#pragma unroll
    for (int n = 0; n < 2; ++n)
#pragma unroll
      for (int kh = 0; kh < 2; ++kh) {
        int rowb = wc * 32 + n * 16 + (lane & 15);
        int byteb = rowb * 128 + kh * 64 + ((lane >> 4) * 16);
        byteb ^= (rowb & 7) << 4;
        bff[n][kh] = *reinterpret_cast<const short8*>(cB + byteb);
      }

    // ---- MFMA ----
#pragma unroll
    for (int m = 0; m < 4; ++m)
#pragma unroll
      for (int n = 0; n < 2; ++n)
#pragma unroll
        for (int kh = 0; kh < 2; ++kh)
          acc[m][n] = __builtin_amdgcn_mfma_f32_16x16x32_bf16(
              af[m][kh], bff[n][kh], acc[m][n], 0, 0, 0);
  }

  // ---- store partial tile ----
  float* g = gpart + ((size_t)s * BATCH + b) * 4 * TILE_ELEMS + (size_t)tile * TILE_ELEMS;
#pragma unroll
  for (int m = 0; m < 4; ++m)
#pragma unroll
    for (int n = 0; n < 2; ++n)
#pragma unroll
      for (int r = 0; r < 4; ++r) {
        int row = wr * 64 + m * 16 + ((lane >> 4) * 4 + r);
        int col = wc * 32 + n * 16 + (lane & 15);
        g[row * 128 + col] = acc[m][n][r];
      }
}

// ---------------------------------------------------------------------------
// K2: fused density + MLP. grid = 32 batches, 1024 threads (16 waves).
//     density[r] = (1/CH) sum_j exp(-0.5*max(sq_r + sq_j - 2 g, 0))
//     sq from Gram diagonal (exact cancellation on diagonal), then
//     scale = sigmoid(relu(density@W1+b1)@W2+b2) + GAMMA in the same block.
// ---------------------------------------------------------------------------
__global__ __launch_bounds__(1024)
void density_mlp_kernel(const float* __restrict__ gpart,
                        const float* __restrict__ w1, const float* __restrict__ b1,
                        const float* __restrict__ w2, const float* __restrict__ b2,
                        float* __restrict__ scale) {
  const int b    = blockIdx.x;
  const int t    = threadIdx.x;
  const int lane = t & 63;
  const int wave = t >> 6;        // 0..15

  __shared__ float sq[CH];
  __shared__ float dens[CH];
  __shared__ float hid[RED];

  if (t < CH) {
    int jt = t >> 7, jr = t & 127;
    size_t off = ((size_t)b * 4 + (size_t)jt * 3) * TILE_ELEMS + (size_t)jr * 128 + jr;
    float v = 0.f;
#pragma unroll
    for (int s = 0; s < NSPLIT; ++s) v += gpart[off + (size_t)s * SLICE_STRIDE];
    sq[t] = v;
  }
  __syncthreads();

  const float* gb = gpart + (size_t)b * 4 * TILE_ELEMS;
#pragma unroll 1
  for (int rr = 0; rr < 16; ++rr) {
    int r = wave * 16 + rr;               // 16 waves x 16 rows = 256
    int rt = r >> 7, rrow = r & 127;
    float sqr = sq[r];
    float ssum = 0.f;
#pragma unroll
    for (int cc = 0; cc < 4; ++cc) {
      int j = cc * 64 + lane;
      int jt = j >> 7;
      size_t off = (size_t)(rt * 2 + jt) * TILE_ELEMS + (size_t)rrow * 128 + (j & 127);
      float g = 0.f;
#pragma unroll
      for (int s = 0; s < NSPLIT; ++s) g += gb[off + (size_t)s * SLICE_STRIDE];
      float d2 = fmaxf(sqr + sq[j] - 2.f * g, 0.f);
      ssum += __expf(-0.5f * d2);
    }
    ssum += __shfl_xor(ssum, 1);
    ssum += __shfl_xor(ssum, 2);
    ssum += __shfl_xor(ssum, 4);
    ssum += __shfl_xor(ssum, 8);
    ssum += __shfl_xor(ssum, 16);
    ssum += __shfl_xor(ssum, 32);
    if (lane == 0) dens[r] = ssum * (1.0f / CH);
  }
  __syncthreads();

  if (t < RED) {
    float s = b1[t];
#pragma unroll 4
    for (int c = 0; c < CH; ++c) s += dens[c] * w1[c * RED + t];
    hid[t] = fmaxf(s, 0.f);
  }
  __syncthreads();

  if (t < CH) {
    float s = b2[t];
#pragma unroll
    for (int h = 0; h < RED; ++h) s += hid[h] * w2[h * CH + t];
    scale[b * CH + t] = 1.f / (1.f + __expf(-s)) + GAMMA;
  }
}

// ---------------------------------------------------------------------------
// K3: out = x * scale[b,c]   (float4 grid-stride)
// ---------------------------------------------------------------------------
__global__ __launch_bounds__(256)
void scale_kernel(const f32x4* __restrict__ x, const float* __restrict__ scale,
                  f32x4* __restrict__ out, int n4) {
  const int stride = gridDim.x * blockDim.x;
  for (int i = blockIdx.x * blockDim.x + threadIdx.x; i < n4; i += stride) {
    float s = scale[i >> 10];          // 1024 float4 per (b,c) row
    out[i] = x[i] * s;
  }
}

extern "C" void kernel_launch(void* const* d_in, const int* in_sizes, int n_in,
                              void* d_out, int out_size, void* d_ws, size_t ws_size,
                              hipStream_t stream) {
  const float* x  = (const float*)d_in[0];
  const float* w1 = (const float*)d_in[1];
  const float* b1 = (const float*)d_in[2];
  const float* w2 = (const float*)d_in[3];
  const float* b2 = (const float*)d_in[4];
  float* out = (float*)d_out;

  float* gpart = (float*)d_ws;                        // 4*32*4*16384 f32 = 33.6 MB
  float* scale = gpart + NSPLIT * SLICE_STRIDE;       // 32*256

  gram_partial_kernel<<<dim3(BATCH * 4 * NSPLIT), dim3(512), 0, stream>>>(x, gpart);
  density_mlp_kernel<<<dim3(BATCH), dim3(1024), 0, stream>>>(gpart, w1, b1, w2, b2, scale);

  const int n4 = BATCH * CH * NSP / 4;
  scale_kernel<<<dim3(4096), dim3(256), 0, stream>>>(
      (const f32x4*)x, scale, (f32x4*)out, n4);
}

// Round 4
// 107.568 us; speedup vs baseline: 1.3836x; 1.3836x over previous
//
#include <hip/hip_runtime.h>
#include <hip/hip_bf16.h>
#include <cstdint>
#include <cstddef>

#define BATCH 32
#define CH    256
#define NSP   4096          // 64*64 spatial
#define RED   64            // CH / 4
#define GAMMA 0.5f
#define NSPLIT 4            // split-K factor
#define KSEG  (NSP / NSPLIT)      // 1024
#define NKT   (KSEG / 64)         // 16 K-iters of 64
#define TILE_ELEMS (128 * 128)
#define SLICE_STRIDE ((size_t)BATCH * 4 * TILE_ELEMS)   // elems per split slice

typedef float f32x4 __attribute__((ext_vector_type(4)));
typedef short short8 __attribute__((ext_vector_type(8)));

static __device__ inline unsigned short bfu(float f) {
  __hip_bfloat16 h = __float2bfloat16(f);   // RNE; compiler emits v_cvt_pk_bf16_f32
  return __builtin_bit_cast(unsigned short, h);
}

// ---------------------------------------------------------------------------
// K1: split-K partial Gram. grid = 32 b * 4 tiles * 4 splits = 512 blocks
//     (2 blocks/CU), 512 threads (8 waves, 2x4 wave grid), 128x128 tile,
//     BK=64, bf16 MFMA.  XCD-aware mapping: batch b's 16 blocks -> XCD b>>2,
//     so x_b (4 MB) lives in that XCD's 4 MB L2 while its blocks run.
//     gpart[s][b][tile][128][128] (f32)
// ---------------------------------------------------------------------------
__global__ __launch_bounds__(512, 4)   // 4 waves/EU min = 2 blocks/CU
void gram_partial_kernel(const float* __restrict__ x, float* __restrict__ gpart) {
  const int bx   = blockIdx.x;       // 0..511
  // XCD-local remap (dispatch round-robins blockIdx % 8 across XCDs):
  const int xcd  = bx & 7;
  const int slot = bx >> 3;          // 0..63 within XCD
  const int b    = xcd * 4 + (slot >> 4);
  const int rem  = slot & 15;
  const int tile = rem >> 2;
  const int s    = rem & 3;
  const int tr   = tile >> 1;
  const int tc   = tile & 1;
  const int tid  = threadIdx.x;
  const int lane = tid & 63;
  const int wave = tid >> 6;
  const int wr   = wave >> 2;        // 0..1  (64-row half)
  const int wc   = wave & 3;         // 0..3  (32-col quarter)

  __shared__ unsigned short lA[128 * 64];    // 16 KiB, XOR-swizzled bf16
  __shared__ unsigned short lB[128 * 64];    // 16 KiB

  const int rsub = tid >> 4;   // 0..31 (row within 32-row group)
  const int c4   = tid & 15;   // float4 column index (64 floats per K-slab row)

  const float* baseA = x + (size_t)(b * CH + tr * 128) * NSP + s * KSEG;
  const float* baseB = x + (size_t)(b * CH + tc * 128) * NSP + s * KSEG;

  f32x4 pa[4], pb[4];
  // prologue: K-tile 0 into registers
#pragma unroll
  for (int i = 0; i < 4; ++i) {
    int row = i * 32 + rsub;
    pa[i] = *reinterpret_cast<const f32x4*>(baseA + (size_t)row * NSP + c4 * 4);
    pb[i] = *reinterpret_cast<const f32x4*>(baseB + (size_t)row * NSP + c4 * 4);
  }

  f32x4 acc[4][2];
#pragma unroll
  for (int m = 0; m < 4; ++m)
#pragma unroll
    for (int n = 0; n < 2; ++n)
      acc[m][n] = (f32x4){0.f, 0.f, 0.f, 0.f};

  char* cA = (char*)lA;
  char* cB = (char*)lB;

  for (int kt = 0; kt < NKT; ++kt) {
    __syncthreads();   // previous iteration's frags fully consumed
    // ---- convert staged registers to bf16 and write to LDS (swizzled) ----
#pragma unroll
    for (int i = 0; i < 4; ++i) {
      int row = i * 32 + rsub;
      int byte = row * 128 + c4 * 8;
      byte ^= (row & 7) << 4;

      uint64_t wa = (uint64_t)bfu(pa[i][0]) | ((uint64_t)bfu(pa[i][1]) << 16) |
                    ((uint64_t)bfu(pa[i][2]) << 32) | ((uint64_t)bfu(pa[i][3]) << 48);
      *reinterpret_cast<uint64_t*>(cA + byte) = wa;

      uint64_t wb = (uint64_t)bfu(pb[i][0]) | ((uint64_t)bfu(pb[i][1]) << 16) |
                    ((uint64_t)bfu(pb[i][2]) << 32) | ((uint64_t)bfu(pb[i][3]) << 48);
      *reinterpret_cast<uint64_t*>(cB + byte) = wb;
    }
    __syncthreads();

    // ---- prefetch next K-slab into registers (overlaps MFMA below) ----
    if (kt + 1 < NKT) {
      const float* kA = baseA + (kt + 1) * 64;
      const float* kB = baseB + (kt + 1) * 64;
#pragma unroll
      for (int i = 0; i < 4; ++i) {
        int row = i * 32 + rsub;
        pa[i] = *reinterpret_cast<const f32x4*>(kA + (size_t)row * NSP + c4 * 4);
        pb[i] = *reinterpret_cast<const f32x4*>(kB + (size_t)row * NSP + c4 * 4);
      }
    }

    // ---- LDS -> fragments ----
    short8 af[4][2], bff[2][2];
#pragma unroll
    for (int m = 0; m < 4; ++m)
#pragma unroll
      for (int kh = 0; kh < 2; ++kh) {
        int rowa = wr * 64 + m * 16 + (lane & 15);
        int bytea = rowa * 128 + kh * 64 + ((lane >> 4) * 16);
        bytea ^= (rowa & 7) << 4;
        af[m][kh] = *reinterpret_cast<const short8*>(cA + bytea);
      }
#pragma unroll
    for (int n = 0; n < 2; ++n)
#pragma unroll
      for (int kh = 0; kh < 2; ++kh) {
        int rowb = wc * 32 + n * 16 + (lane & 15);
        int byteb = rowb * 128 + kh * 64 + ((lane >> 4) * 16);
        byteb ^= (rowb & 7) << 4;
        bff[n][kh] = *reinterpret_cast<const short8*>(cB + byteb);
      }

    // ---- MFMA ----
#pragma unroll
    for (int m = 0; m < 4; ++m)
#pragma unroll
      for (int n = 0; n < 2; ++n)
#pragma unroll
        for (int kh = 0; kh < 2; ++kh)
          acc[m][n] = __builtin_amdgcn_mfma_f32_16x16x32_bf16(
              af[m][kh], bff[n][kh], acc[m][n], 0, 0, 0);
  }

  // ---- store partial tile ----
  float* g = gpart + ((size_t)s * BATCH + b) * 4 * TILE_ELEMS + (size_t)tile * TILE_ELEMS;
#pragma unroll
  for (int m = 0; m < 4; ++m)
#pragma unroll
    for (int n = 0; n < 2; ++n)
#pragma unroll
      for (int r = 0; r < 4; ++r) {
        int row = wr * 64 + m * 16 + ((lane >> 4) * 4 + r);
        int col = wc * 32 + n * 16 + (lane & 15);
        g[row * 128 + col] = acc[m][n][r];
      }
}

// ---------------------------------------------------------------------------
// K2: density. grid = 32 b * 8 row-groups = 256 blocks, 256 threads (4 waves,
//     8 rows/wave). sq from Gram diagonal (exact cancellation on diagonal).
//     density[b][r] = (1/CH) sum_j exp(-0.5*max(sq_r + sq_j - 2 g, 0))
// ---------------------------------------------------------------------------
__global__ __launch_bounds__(256)
void density_kernel(const float* __restrict__ gpart, float* __restrict__ density) {
  const int blk  = blockIdx.x;   // 0..255
  const int b    = blk >> 3;
  const int rg   = blk & 7;      // 32-row group
  const int t    = threadIdx.x;
  const int lane = t & 63;
  const int wave = t >> 6;       // 0..3

  __shared__ float sq[CH];
  {
    int jt = t >> 7, jr = t & 127;
    size_t off = ((size_t)b * 4 + (size_t)jt * 3) * TILE_ELEMS + (size_t)jr * 128 + jr;
    float v = 0.f;
#pragma unroll
    for (int s = 0; s < NSPLIT; ++s) v += gpart[off + (size_t)s * SLICE_STRIDE];
    sq[t] = v;
  }
  __syncthreads();

  const float* gb = gpart + (size_t)b * 4 * TILE_ELEMS;
#pragma unroll 1
  for (int rr = 0; rr < 8; ++rr) {
    int r = rg * 32 + wave * 8 + rr;
    int rt = r >> 7, rrow = r & 127;
    float sqr = sq[r];
    float ssum = 0.f;
#pragma unroll
    for (int cc = 0; cc < 4; ++cc) {
      int j = cc * 64 + lane;
      int jt = j >> 7;
      size_t off = (size_t)(rt * 2 + jt) * TILE_ELEMS + (size_t)rrow * 128 + (j & 127);
      float g = 0.f;
#pragma unroll
      for (int s = 0; s < NSPLIT; ++s) g += gb[off + (size_t)s * SLICE_STRIDE];
      float d2 = fmaxf(sqr + sq[j] - 2.f * g, 0.f);
      ssum += __expf(-0.5f * d2);
    }
    ssum += __shfl_xor(ssum, 1);
    ssum += __shfl_xor(ssum, 2);
    ssum += __shfl_xor(ssum, 4);
    ssum += __shfl_xor(ssum, 8);
    ssum += __shfl_xor(ssum, 16);
    ssum += __shfl_xor(ssum, 32);
    if (lane == 0) density[b * CH + r] = ssum * (1.0f / CH);
  }
}

// ---------------------------------------------------------------------------
// K3: per-batch MLP  scale = sigmoid(relu(density@W1+b1)@W2+b2) + GAMMA
// ---------------------------------------------------------------------------
__global__ __launch_bounds__(256)
void mlp_kernel(const float* __restrict__ density,
                const float* __restrict__ w1, const float* __restrict__ b1,
                const float* __restrict__ w2, const float* __restrict__ b2,
                float* __restrict__ scale) {
  const int b = blockIdx.x;
  const int t = threadIdx.x;
  __shared__ float dens[CH];
  __shared__ float hid[RED];
  dens[t] = density[b * CH + t];
  __syncthreads();
  if (t < RED) {
    float s = b1[t];
#pragma unroll 4
    for (int c = 0; c < CH; ++c) s += dens[c] * w1[c * RED + t];
    hid[t] = fmaxf(s, 0.f);
  }
  __syncthreads();
  float s = b2[t];
#pragma unroll
  for (int h = 0; h < RED; ++h) s += hid[h] * w2[h * CH + t];
  scale[b * CH + t] = 1.f / (1.f + __expf(-s)) + GAMMA;
}

// ---------------------------------------------------------------------------
// K4: out = x * scale[b,c]   (float4 grid-stride, nontemporal stores)
// ---------------------------------------------------------------------------
__global__ __launch_bounds__(256)
void scale_kernel(const f32x4* __restrict__ x, const float* __restrict__ scale,
                  f32x4* __restrict__ out, int n4) {
  const int stride = gridDim.x * blockDim.x;
  for (int i = blockIdx.x * blockDim.x + threadIdx.x; i < n4; i += stride) {
    float s = scale[i >> 10];          // 1024 float4 per (b,c) row
    __builtin_nontemporal_store(x[i] * s, &out[i]);
  }
}

extern "C" void kernel_launch(void* const* d_in, const int* in_sizes, int n_in,
                              void* d_out, int out_size, void* d_ws, size_t ws_size,
                              hipStream_t stream) {
  const float* x  = (const float*)d_in[0];
  const float* w1 = (const float*)d_in[1];
  const float* b1 = (const float*)d_in[2];
  const float* w2 = (const float*)d_in[3];
  const float* b2 = (const float*)d_in[4];
  float* out = (float*)d_out;

  float* gpart   = (float*)d_ws;                        // 4*32*4*16384 f32 = 33.6 MB
  float* density = gpart + NSPLIT * SLICE_STRIDE;       // 32*256
  float* scale   = density + BATCH * CH;                // 32*256

  gram_partial_kernel<<<dim3(BATCH * 4 * NSPLIT), dim3(512), 0, stream>>>(x, gpart);
  density_kernel<<<dim3(BATCH * 8), dim3(256), 0, stream>>>(gpart, density);
  mlp_kernel<<<dim3(BATCH), dim3(256), 0, stream>>>(density, w1, b1, w2, b2, scale);

  const int n4 = BATCH * CH * NSP / 4;
  scale_kernel<<<dim3(4096), dim3(256), 0, stream>>>(
      (const f32x4*)x, scale, (f32x4*)out, n4);
}